// Round 1
// baseline (787.334 us; speedup 1.0000x reference)
//
#include <hip/hip_runtime.h>
#include <math.h>

#define NB 4
#define NC 64
#define NHW 64
#define NL 1024   // 32x32 kernel-patch grid
#define NP 3969   // 63x63 correlation positions
#define PHW 63

// ---------------- kernel 1: per-(b,c) inverse L2 norm of b ----------------
__global__ __launch_bounds__(256) void norm_kernel(const float* __restrict__ bsrc,
                                                   float* __restrict__ invn) {
    int bc = blockIdx.x;  // 0..255
    const float* src = bsrc + (size_t)bc * 4096;
    float s = 0.f;
    for (int i = threadIdx.x; i < 4096; i += 256) { float v = src[i]; s += v * v; }
#pragma unroll
    for (int off = 32; off > 0; off >>= 1) s += __shfl_down(s, off, 64);
    __shared__ float part[4];
    if ((threadIdx.x & 63) == 0) part[threadIdx.x >> 6] = s;
    __syncthreads();
    if (threadIdx.x == 0) {
        float t = part[0] + part[1] + part[2] + part[3];
        invn[bc] = 1.0f / sqrtf(t + 1e-8f);
    }
}

// ---------------- kernel 2: patch means of (1-mask) -----------------------
// mmk[b][l]  : stride-2 patches (kernel grid, 32x32)
// mmp[b][p]  : stride-1 patches (correlation grid, 63x63)
__global__ __launch_bounds__(256) void stats_kernel(const float* __restrict__ mask,
                                                    float* __restrict__ mmk,
                                                    float* __restrict__ mmp) {
    int id = blockIdx.x * 256 + threadIdx.x;
    if (id < NB * NL) {
        int b = id >> 10, l = id & 1023;
        int lh = l >> 5, lw = l & 31;
        const float* m = mask + b * 4096;
        float s = 0.f;
#pragma unroll
        for (int i = 0; i < 4; ++i) {
            int r = 2 * lh - 1 + i; r = min(max(r, 0), 63);
#pragma unroll
            for (int j = 0; j < 4; ++j) {
                int c = 2 * lw - 1 + j; c = min(max(c, 0), 63);
                s += 1.0f - m[r * 64 + c];
            }
        }
        mmk[id] = s * (1.0f / 16.0f);
    } else {
        int id2 = id - NB * NL;
        if (id2 < NB * NP) {
            int b = id2 / NP, p = id2 - b * NP;
            int ph = p / PHW, pw = p - ph * PHW;
            const float* m = mask + b * 4096;
            float s = 0.f;
#pragma unroll
            for (int i = 0; i < 4; ++i) {
                int r = ph - 1 + i; r = min(max(r, 0), 63);
#pragma unroll
                for (int j = 0; j < 4; ++j) {
                    int c = pw - 1 + j; c = min(max(c, 0), 63);
                    s += 1.0f - m[r * 64 + c];
                }
            }
            mmp[id2] = s * (1.0f / 16.0f);
        }
    }
}

// ---------------- kernel 3: the big correlation GEMM ----------------------
// Rt[b][p][l] = sum_{c,i,j} bn[b,c, clamp(2lh-1+i), clamp(2lw-1+j)]
//                         *  f[b,c, clamp(ph-1+i),  clamp(pw-1+j)]
// One block: 64 l  x 63 pw (one ph row). K-loop over channels (BK=16 = one c).
__global__ __launch_bounds__(256) void gemm_kernel(const float* __restrict__ bsrc,
                                                   const float* __restrict__ fsrcg,
                                                   const float* __restrict__ invn,
                                                   float* __restrict__ Rt) {
    __shared__ float As[16 * 64];   // As[kk][ll]
    __shared__ float Bs[16 * 64];   // Bs[kk][pp]
    __shared__ float Ct[64 * 68];   // Ct[p_local][l_local], stride 68 (16B aligned)

    int l0 = blockIdx.x * 64;   // l-tile
    int ph = blockIdx.y;        // 0..62
    int b  = blockIdx.z;
    int tid = threadIdx.x;
    int tx = tid & 15, ty = tid >> 4;

    float acc[4][4] = {{0.f}};

    const float* bb = bsrc  + (size_t)b * (NC * 4096);
    const float* fb = fsrcg + (size_t)b * (NC * 4096);

    for (int c = 0; c < NC; ++c) {
        float scale = invn[b * NC + c];
        const float* bchan = bb + c * 4096;
        const float* fchan = fb + c * 4096;
        // A tile: 64 l x 16 kk, 4 elems/thread
#pragma unroll
        for (int q = 0; q < 4; ++q) {
            int e = tid * 4 + q;
            int ll = e >> 4, kk = e & 15;
            int l = l0 + ll;
            int lh = l >> 5, lw = l & 31;
            int i = kk >> 2, j = kk & 3;
            int r = min(max(2 * lh - 1 + i, 0), 63);
            int s = min(max(2 * lw - 1 + j, 0), 63);
            As[kk * 64 + ll] = bchan[r * 64 + s] * scale;
        }
        // B tile: 16 kk x 64 pp (pp=63 padded with 0), coalesced
#pragma unroll
        for (int q = 0; q < 4; ++q) {
            int e = tid + 256 * q;
            int kk = e >> 6, pp = e & 63;
            int i = kk >> 2, j = kk & 3;
            float v = 0.f;
            if (pp < 63) {
                int r = min(max(ph - 1 + i, 0), 63);
                int s = min(max(pp - 1 + j, 0), 63);
                v = fchan[r * 64 + s];
            }
            Bs[kk * 64 + pp] = v;
        }
        __syncthreads();
#pragma unroll
        for (int kk = 0; kk < 16; ++kk) {
            float4 a4 = *(const float4*)&As[kk * 64 + ty * 4];
            float4 b4 = *(const float4*)&Bs[kk * 64 + tx * 4];
            float av[4] = {a4.x, a4.y, a4.z, a4.w};
            float bv[4] = {b4.x, b4.y, b4.z, b4.w};
#pragma unroll
            for (int a = 0; a < 4; ++a)
#pragma unroll
                for (int q = 0; q < 4; ++q) acc[a][q] += av[a] * bv[q];
        }
        __syncthreads();
    }
    // stage transpose in LDS, then coalesced store to Rt[b][p][l]
#pragma unroll
    for (int a = 0; a < 4; ++a)
#pragma unroll
        for (int q = 0; q < 4; ++q)
            Ct[(tx * 4 + q) * 68 + ty * 4 + a] = acc[a][q];
    __syncthreads();
    for (int idx = tid; idx < 63 * 16; idx += 256) {
        int pl = idx >> 4, ch = idx & 15;
        float4 v = *(const float4*)&Ct[pl * 68 + ch * 4];
        size_t p = (size_t)ph * PHW + pl;
        *(float4*)(Rt + (((size_t)b * NP + p) * NL + l0 + ch * 4)) = v;
    }
}

// ---------------- kernel 4: stencil + mask + softmax ----------------------
// F[l,p] = sum_{d,e in {-1,0,1}} R[t(t(l)+d)+e, tp(tp(p)+d)+e]  (bounds-checked)
// out[b,l,ph,pw] = softmax_l( F * mm * 10 )
#define FS_STRIDE 1028
__global__ __launch_bounds__(256) void epilogue_kernel(const float* __restrict__ Rt,
                                                       const float* __restrict__ mmkA,
                                                       const float* __restrict__ mmpA,
                                                       float* __restrict__ out) {
    __shared__ float Fs[8 * FS_STRIDE];
    __shared__ float gsum[8];
    int ph  = blockIdx.x;        // 0..62
    int pw0 = blockIdx.y * 8;    // 8 pw per block
    int b   = blockIdx.z;
    int tid = threadIdx.x;

    // ---- phase 1: fill Fs[pwl][l] with masked, scaled logits ----
    {
        int pwl = tid & 7, lpart = tid >> 3;   // lpart 0..31
        int pw = pw0 + pwl;
        bool pvalid = pw < PHW;
        int p = ph * PHW + pw;
        const float* Rb = Rt + (size_t)b * NP * NL;
        float mmpv = 0.f;
        int p2arr[3]; int pokm = 0;
        if (pvalid) {
            mmpv = mmpA[b * NP + p];
            int tp = pw * PHW + ph;            // transpose-involution on 63x63 flat
#pragma unroll
            for (int dd = 0; dd < 3; ++dd) {
                int pq = tp + dd - 1;
                if (pq >= 0 && pq < NP) {
                    int qh = pq / PHW, qw = pq - qh * PHW;
                    p2arr[dd] = qw * PHW + qh;
                    pokm |= (1 << dd);
                } else p2arr[dd] = 0;
            }
        } else { p2arr[0] = p2arr[1] = p2arr[2] = 0; }

        for (int k = 0; k < 32; ++k) {
            int l = lpart + (k << 5);
            int tl = ((l & 31) << 5) | (l >> 5); // transpose-involution on 32x32 flat
            float Fv = 0.f;
#pragma unroll
            for (int dd = 0; dd < 3; ++dd) {
                int lq = tl + dd - 1;
                if (((pokm >> dd) & 1) && lq >= 0 && lq < NL) {
                    int l2 = ((lq & 31) << 5) | (lq >> 5);
                    int p2 = p2arr[dd];
#pragma unroll
                    for (int ee = 0; ee < 3; ++ee) {
                        int l3 = l2 + ee - 1;
                        int p3 = p2 + ee - 1;
                        if (l3 >= 0 && l3 < NL && p3 >= 0 && p3 < NP)
                            Fv += Rb[(size_t)p3 * NL + l3];
                    }
                }
            }
            float mmkv = mmkA[b * NL + l];
            float mmv = (((mmkv > mmpv) && (mmpv > 0.5f)) || (mmkv == 1.0f)) ? 1.0f : 0.0f;
            float logit = pvalid ? (Fv * mmv * 10.0f) : 0.0f;
            Fs[pwl * FS_STRIDE + l] = logit;
        }
    }
    __syncthreads();

    // ---- phase 2: per-pw softmax (max, exp, sum); 32 lanes per pw column ----
    {
        int pw2 = tid >> 5;      // 0..7
        int tl  = tid & 31;
        float m = -3.0e38f;
        for (int k = 0; k < 32; ++k)
            m = fmaxf(m, Fs[pw2 * FS_STRIDE + tl + (k << 5)]);
#pragma unroll
        for (int off = 16; off >= 1; off >>= 1) m = fmaxf(m, __shfl_xor(m, off, 64));
        float s = 0.f;
        for (int k = 0; k < 32; ++k) {
            int idx = pw2 * FS_STRIDE + tl + (k << 5);
            float e = expf(Fs[idx] - m);
            Fs[idx] = e;
            s += e;
        }
#pragma unroll
        for (int off = 16; off >= 1; off >>= 1) s += __shfl_xor(s, off, 64);
        if (tl == 0) gsum[pw2] = s;
    }
    __syncthreads();

    // ---- phase 3: normalized write, coalesced over pw ----
    {
        int pwl = tid & 7, lp3 = tid >> 3;  // lp3 0..31
        int pw = pw0 + pwl;
        bool pvalid = pw < PHW;
        float rinv = 1.0f / gsum[pwl];
        if (pvalid) {
            int p = ph * PHW + pw;
            for (int k = 0; k < 32; ++k) {
                int l = lp3 + (k << 5);
                float v = Fs[pwl * FS_STRIDE + l] * rinv;
                out[((size_t)(b * NL + l)) * NP + p] = v;
            }
        }
    }
}

extern "C" void kernel_launch(void* const* d_in, const int* in_sizes, int n_in,
                              void* d_out, int out_size, void* d_ws, size_t ws_size,
                              hipStream_t stream) {
    const float* f    = (const float*)d_in[0];
    const float* b    = (const float*)d_in[1];
    const float* mask = (const float*)d_in[2];
    float* out = (float*)d_out;

    float* ws   = (float*)d_ws;
    float* Rt   = ws;                      // 4*3969*1024 = 16,257,024 floats
    float* invn = ws + 16257024;           // 256
    float* mmk  = invn + 256;              // 4096
    float* mmp  = mmk + 4096;              // 15876  (total ~62.1 MB)

    norm_kernel<<<dim3(256), dim3(256), 0, stream>>>(b, invn);
    stats_kernel<<<dim3(79), dim3(256), 0, stream>>>(mask, mmk, mmp);
    gemm_kernel<<<dim3(16, 63, 4), dim3(256), 0, stream>>>(b, f, invn, Rt);
    epilogue_kernel<<<dim3(63, 8, 4), dim3(256), 0, stream>>>(Rt, mmk, mmp, out);
}

// Round 2
// 402.677 us; speedup vs baseline: 1.9552x; 1.9552x over previous
//
#include <hip/hip_runtime.h>
#include <math.h>

#define NB 4
#define NC 64
#define NL 1024   // 32x32 kernel-patch grid
#define NP 3969   // 63x63 correlation positions
#define PHW 63

typedef unsigned short ushort_t;
typedef __attribute__((ext_vector_type(8))) short short8;
typedef __attribute__((ext_vector_type(16))) float floatx16;

// ---------------- kernel 1: per-(b,c) inverse L2 norm of b ----------------
__global__ __launch_bounds__(256) void norm_kernel(const float* __restrict__ bsrc,
                                                   float* __restrict__ invn) {
    int bc = blockIdx.x;  // 0..255
    const float* src = bsrc + (size_t)bc * 4096;
    float s = 0.f;
    for (int i = threadIdx.x; i < 4096; i += 256) { float v = src[i]; s += v * v; }
#pragma unroll
    for (int off = 32; off > 0; off >>= 1) s += __shfl_down(s, off, 64);
    __shared__ float part[4];
    if ((threadIdx.x & 63) == 0) part[threadIdx.x >> 6] = s;
    __syncthreads();
    if (threadIdx.x == 0) {
        float t = part[0] + part[1] + part[2] + part[3];
        invn[bc] = 1.0f / sqrtf(t + 1e-8f);
    }
}

// ---------------- kernel 2: patch means of (1-mask) -----------------------
__global__ __launch_bounds__(256) void stats_kernel(const float* __restrict__ mask,
                                                    float* __restrict__ mmk,
                                                    float* __restrict__ mmp) {
    int id = blockIdx.x * 256 + threadIdx.x;
    if (id < NB * NL) {
        int b = id >> 10, l = id & 1023;
        int lh = l >> 5, lw = l & 31;
        const float* m = mask + b * 4096;
        float s = 0.f;
#pragma unroll
        for (int i = 0; i < 4; ++i) {
            int r = min(max(2 * lh - 1 + i, 0), 63);
#pragma unroll
            for (int j = 0; j < 4; ++j) {
                int c = min(max(2 * lw - 1 + j, 0), 63);
                s += 1.0f - m[r * 64 + c];
            }
        }
        mmk[id] = s * (1.0f / 16.0f);
    } else {
        int id2 = id - NB * NL;
        if (id2 < NB * NP) {
            int b = id2 / NP, p = id2 - b * NP;
            int ph = p / PHW, pw = p - ph * PHW;
            const float* m = mask + b * 4096;
            float s = 0.f;
#pragma unroll
            for (int i = 0; i < 4; ++i) {
                int r = min(max(ph - 1 + i, 0), 63);
#pragma unroll
                for (int j = 0; j < 4; ++j) {
                    int c = min(max(pw - 1 + j, 0), 63);
                    s += 1.0f - m[r * 64 + c];
                }
            }
            mmp[id2] = s * (1.0f / 16.0f);
        }
    }
}

// ------------- split helper: fp32 -> bf16 hi + bf16 residual --------------
__device__ inline void split_bf16(float v, ushort_t& hv, ushort_t& lv) {
    unsigned u = __float_as_uint(v);
    unsigned rr = u + 0x7FFFu + ((u >> 16) & 1u);
    hv = (ushort_t)(rr >> 16);
    float fh = __uint_as_float(((unsigned)hv) << 16);
    float remv = v - fh;
    unsigned u2 = __float_as_uint(remv);
    unsigned rr2 = u2 + 0x7FFFu + ((u2 >> 16) & 1u);
    lv = (ushort_t)(rr2 >> 16);
}

// ---------------- kernel 3a: unfold + normalize + split A (bn patches) ----
// A[b][l][k], k = c*16 + i*4 + j
__global__ __launch_bounds__(256) void splitA_kernel(const float* __restrict__ bsrc,
                                                     const float* __restrict__ invn,
                                                     ushort_t* __restrict__ Ahi,
                                                     ushort_t* __restrict__ Alo) {
    int g = blockIdx.x * 256 + threadIdx.x;   // 0..262143
    int b = g >> 16;
    int rem = g & 65535;
    int l = rem >> 6, c = rem & 63;
    int lh = l >> 5, lw = l & 31;
    float scale = invn[(b << 6) + c];
    const float* src = bsrc + (((size_t)((b << 6) + c)) << 12);
    __align__(16) ushort_t h[16];
    __align__(16) ushort_t lo[16];
#pragma unroll
    for (int i = 0; i < 4; ++i) {
        int r = min(max(2 * lh - 1 + i, 0), 63);
#pragma unroll
        for (int j = 0; j < 4; ++j) {
            int s = min(max(2 * lw - 1 + j, 0), 63);
            float v = src[(r << 6) + s] * scale;
            split_bf16(v, h[i * 4 + j], lo[i * 4 + j]);
        }
    }
    size_t base = ((((size_t)b << 10) + l) << 10) + (c << 4);
    *(uint4*)(Ahi + base)     = *(uint4*)h;
    *(uint4*)(Ahi + base + 8) = *(uint4*)(h + 8);
    *(uint4*)(Alo + base)     = *(uint4*)lo;
    *(uint4*)(Alo + base + 8) = *(uint4*)(lo + 8);
}

// ---------------- kernel 3b: unfold + split B (f patches) -----------------
// B[b][p][k], k = c*16 + i*4 + j
__global__ __launch_bounds__(256) void splitB_kernel(const float* __restrict__ fsrc,
                                                     ushort_t* __restrict__ Bhi,
                                                     ushort_t* __restrict__ Blo) {
    int tid = threadIdx.x;
    int p = blockIdx.x * 4 + (tid >> 6);
    int b = blockIdx.y;
    int c = tid & 63;
    if (p >= NP) return;
    int ph = p / PHW, pw = p - ph * PHW;
    const float* src = fsrc + (((size_t)((b << 6) + c)) << 12);
    __align__(16) ushort_t h[16];
    __align__(16) ushort_t lo[16];
#pragma unroll
    for (int i = 0; i < 4; ++i) {
        int r = min(max(ph - 1 + i, 0), 63);
#pragma unroll
        for (int j = 0; j < 4; ++j) {
            int s = min(max(pw - 1 + j, 0), 63);
            split_bf16(src[(r << 6) + s], h[i * 4 + j], lo[i * 4 + j]);
        }
    }
    size_t base = (((size_t)b * NP + p) << 10) + (c << 4);
    *(uint4*)(Bhi + base)     = *(uint4*)h;
    *(uint4*)(Bhi + base + 8) = *(uint4*)(h + 8);
    *(uint4*)(Blo + base)     = *(uint4*)lo;
    *(uint4*)(Blo + base + 8) = *(uint4*)(lo + 8);
}

// ---------------- kernel 4: MFMA GEMM, split-bf16 3-product ---------------
// Rt[b][p][l] = sum_k B[p][k] * A[l][k]
// Block 128l x 128p, 4 waves in 2x2, wave tile 64x64 = 2x2 of 32x32x16 MFMA.
// LDS chunk layout: s[cc][row][8] : 16B fragment-native (cc = k-chunk 0..3).
__global__ __launch_bounds__(256) void gemm_kernel(
    const ushort_t* __restrict__ Ahi, const ushort_t* __restrict__ Alo,
    const ushort_t* __restrict__ Bhi, const ushort_t* __restrict__ Blo,
    float* __restrict__ Rt) {
    __shared__ ushort_t sAh[4096], sAl[4096], sBh[4096], sBl[4096];

    int l0 = blockIdx.x << 7;
    int p0 = blockIdx.y << 7;
    int b  = blockIdx.z;
    int tid = threadIdx.x;
    int lane = tid & 63, wave = tid >> 6;
    int srow = tid >> 1, shalf = tid & 1;

    const ushort_t* gAh = Ahi + ((size_t)b << 20) + (((size_t)(l0 + srow)) << 10) + (shalf << 4);
    const ushort_t* gAl = Alo + ((size_t)b << 20) + (((size_t)(l0 + srow)) << 10) + (shalf << 4);
    bool pv = (p0 + srow) < NP;
    size_t bgoff = ((size_t)b * NP + (size_t)(p0 + srow)) << 10;
    const ushort_t* gBh = Bhi + bgoff + (shalf << 4);
    const ushort_t* gBl = Blo + bgoff + (shalf << 4);

    floatx16 acc[2][2];
#pragma unroll
    for (int a = 0; a < 2; ++a)
#pragma unroll
        for (int q = 0; q < 2; ++q)
#pragma unroll
            for (int r = 0; r < 16; ++r) acc[a][q][r] = 0.f;

    int pq = (wave & 1) << 6, lq = (wave >> 1) << 6;
    int x = lane & 31, kg = lane >> 5;
    int wbase = (((shalf << 1) << 7) + srow) << 3;   // ushort idx of chunk (2*shalf, srow)

    for (int kb = 0; kb < 32; ++kb) {
        int koff = kb << 5;
        short8 z = {0, 0, 0, 0, 0, 0, 0, 0};
        short8 vah0 = *(const short8*)(gAh + koff);
        short8 vah1 = *(const short8*)(gAh + koff + 8);
        short8 val0 = *(const short8*)(gAl + koff);
        short8 val1 = *(const short8*)(gAl + koff + 8);
        short8 vbh0 = pv ? *(const short8*)(gBh + koff)     : z;
        short8 vbh1 = pv ? *(const short8*)(gBh + koff + 8) : z;
        short8 vbl0 = pv ? *(const short8*)(gBl + koff)     : z;
        short8 vbl1 = pv ? *(const short8*)(gBl + koff + 8) : z;
        __syncthreads();   // previous iteration's frag reads done
        *(short8*)(sAh + wbase)        = vah0;
        *(short8*)(sAh + wbase + 1024) = vah1;
        *(short8*)(sAl + wbase)        = val0;
        *(short8*)(sAl + wbase + 1024) = val1;
        *(short8*)(sBh + wbase)        = vbh0;
        *(short8*)(sBh + wbase + 1024) = vbh1;
        *(short8*)(sBl + wbase)        = vbl0;
        *(short8*)(sBl + wbase + 1024) = vbl1;
        __syncthreads();
#pragma unroll
        for (int h = 0; h < 2; ++h) {
            int cc = (h << 1) + kg;
            int cbase = cc << 10;   // cc*128*8 ushorts
            short8 fAh[2], fAl[2], fBh[2], fBl[2];
#pragma unroll
            for (int t = 0; t < 2; ++t) {
                int ai = cbase + ((lq + (t << 5) + x) << 3);
                int bi = cbase + ((pq + (t << 5) + x) << 3);
                fAh[t] = *(const short8*)(sAh + ai);
                fAl[t] = *(const short8*)(sAl + ai);
                fBh[t] = *(const short8*)(sBh + bi);
                fBl[t] = *(const short8*)(sBl + bi);
            }
#pragma unroll
            for (int pt = 0; pt < 2; ++pt)
#pragma unroll
                for (int lt = 0; lt < 2; ++lt) {
                    acc[pt][lt] = __builtin_amdgcn_mfma_f32_32x32x16_bf16(fBh[pt], fAh[lt], acc[pt][lt], 0, 0, 0);
                    acc[pt][lt] = __builtin_amdgcn_mfma_f32_32x32x16_bf16(fBh[pt], fAl[lt], acc[pt][lt], 0, 0, 0);
                    acc[pt][lt] = __builtin_amdgcn_mfma_f32_32x32x16_bf16(fBl[pt], fAh[lt], acc[pt][lt], 0, 0, 0);
                }
        }
    }
    // store: D row = p (first operand), col = l (second operand)
#pragma unroll
    for (int pt = 0; pt < 2; ++pt)
#pragma unroll
        for (int lt = 0; lt < 2; ++lt)
#pragma unroll
            for (int r = 0; r < 16; ++r) {
                int p = p0 + pq + (pt << 5) + (r & 3) + ((r >> 2) << 3) + (kg << 2);
                int l = l0 + lq + (lt << 5) + x;
                if (p < NP) Rt[((size_t)b * NP + p) * NL + l] = acc[pt][lt][r];
            }
}

// ---------------- kernel 5: first diag3 pass ------------------------------
// D1[p][l] = Rt[p-1][l-1] + Rt[p][l] + Rt[p+1][l+1]   (flat-index zero pad)
__global__ __launch_bounds__(256) void diag1_kernel(const float* __restrict__ Rt,
                                                    float* __restrict__ D1) {
    int p = blockIdx.x, b = blockIdx.y;
    int t = threadIdx.x;
    const float* base = Rt + ((size_t)b * NP + p) * NL;
    int l4 = t << 2;
    float4 r = *(const float4*)(base + l4);
    if (p > 0) {
        const float* pm = base - NL;
        r.x += (l4 > 0) ? pm[l4 - 1] : 0.f;
        r.y += pm[l4];
        r.z += pm[l4 + 1];
        r.w += pm[l4 + 2];
    }
    if (p < NP - 1) {
        const float* pp = base + NL;
        r.x += pp[l4 + 1];
        r.y += pp[l4 + 2];
        r.z += pp[l4 + 3];
        r.w += (l4 + 4 < NL) ? pp[l4 + 4] : 0.f;
    }
    *(float4*)(D1 + ((size_t)b * NP + p) * NL + l4) = r;
}

// ---------------- kernel 6: second diag3 (transposed) + mask + softmax ----
// F[l,p] = sum_{d} D1[tp(tp(p)+d)][tl(tl(l)+d)]  (bounds-checked)
#define FS_STRIDE 1028
__global__ __launch_bounds__(256) void epilogue_kernel(const float* __restrict__ D1,
                                                       const float* __restrict__ mmkA,
                                                       const float* __restrict__ mmpA,
                                                       float* __restrict__ out) {
    __shared__ float Fs[8 * FS_STRIDE];
    __shared__ float gsum[8];
    int ph  = blockIdx.x;        // 0..62
    int pw0 = blockIdx.y * 8;    // 8 pw per block
    int b   = blockIdx.z;
    int tid = threadIdx.x;

    // ---- phase 1: fill Fs[pwl][l] with masked, scaled logits ----
    {
        int pwl = tid & 7, lpart = tid >> 3;   // lpart 0..31
        int pw = pw0 + pwl;
        bool pvalid = pw < PHW;
        int p = ph * PHW + pw;
        const float* Db = D1 + (size_t)b * NP * NL;
        float mmpv = 0.f;
        int p2arr[3]; int pokm = 0;
        if (pvalid) {
            mmpv = mmpA[b * NP + p];
            int tp = pw * PHW + ph;            // transpose-involution on 63x63 flat
#pragma unroll
            for (int dd = 0; dd < 3; ++dd) {
                int pq2 = tp + dd - 1;
                if (pq2 >= 0 && pq2 < NP) {
                    int qh = pq2 / PHW, qw = pq2 - qh * PHW;
                    p2arr[dd] = qw * PHW + qh;
                    pokm |= (1 << dd);
                } else p2arr[dd] = 0;
            }
        } else { p2arr[0] = p2arr[1] = p2arr[2] = 0; }

        for (int k = 0; k < 32; ++k) {
            int l = lpart + (k << 5);
            int tl = ((l & 31) << 5) | (l >> 5); // transpose-involution on 32x32 flat
            float Fv = 0.f;
#pragma unroll
            for (int dd = 0; dd < 3; ++dd) {
                int lqi = tl + dd - 1;
                if (((pokm >> dd) & 1) && lqi >= 0 && lqi < NL) {
                    int l2 = ((lqi & 31) << 5) | (lqi >> 5);
                    Fv += Db[(size_t)p2arr[dd] * NL + l2];
                }
            }
            float mmkv = mmkA[b * NL + l];
            float mmv = (((mmkv > mmpv) && (mmpv > 0.5f)) || (mmkv == 1.0f)) ? 1.0f : 0.0f;
            float logit = pvalid ? (Fv * mmv * 10.0f) : 0.0f;
            Fs[pwl * FS_STRIDE + l] = logit;
        }
    }
    __syncthreads();

    // ---- phase 2: per-pw softmax; 32 lanes per pw column ----
    {
        int pw2 = tid >> 5;      // 0..7
        int tl  = tid & 31;
        float m = -3.0e38f;
        for (int k = 0; k < 32; ++k)
            m = fmaxf(m, Fs[pw2 * FS_STRIDE + tl + (k << 5)]);
#pragma unroll
        for (int off = 16; off >= 1; off >>= 1) m = fmaxf(m, __shfl_xor(m, off, 64));
        float s = 0.f;
        for (int k = 0; k < 32; ++k) {
            int idx = pw2 * FS_STRIDE + tl + (k << 5);
            float e = expf(Fs[idx] - m);
            Fs[idx] = e;
            s += e;
        }
#pragma unroll
        for (int off = 16; off >= 1; off >>= 1) s += __shfl_xor(s, off, 64);
        if (tl == 0) gsum[pw2] = s;
    }
    __syncthreads();

    // ---- phase 3: normalized write, coalesced over pw ----
    {
        int pwl = tid & 7, lp3 = tid >> 3;
        int pw = pw0 + pwl;
        bool pvalid = pw < PHW;
        float rinv = 1.0f / gsum[pwl];
        if (pvalid) {
            int p = ph * PHW + pw;
            for (int k = 0; k < 32; ++k) {
                int l = lp3 + (k << 5);
                float v = Fs[pwl * FS_STRIDE + l] * rinv;
                out[((size_t)(b * NL + l)) * NP + p] = v;
            }
        }
    }
}

extern "C" void kernel_launch(void* const* d_in, const int* in_sizes, int n_in,
                              void* d_out, int out_size, void* d_ws, size_t ws_size,
                              hipStream_t stream) {
    const float* f    = (const float*)d_in[0];
    const float* b    = (const float*)d_in[1];
    const float* mask = (const float*)d_in[2];
    float* out = (float*)d_out;

    // workspace layout (bytes):
    //   Rt : 16,257,024 f32 = 65,028,096 B
    //   AB : Ahi(4,194,304) Alo(4,194,304) Bhi(16,257,024) Blo(16,257,024) ushort
    //        = 40,902,656 ushort = 81,805,312 B   (D1 f32, 65 MB, OVERLAYS this after GEMM)
    //   invn/mmk/mmp floats
    float* Rt = (float*)d_ws;
    ushort_t* AB = (ushort_t*)(Rt + 16257024);
    ushort_t* Ahi = AB;
    ushort_t* Alo = Ahi + 4194304;
    ushort_t* Bhi = Alo + 4194304;
    ushort_t* Blo = Bhi + 16257024;
    float* D1 = (float*)AB;                    // overlay, used after GEMM
    float* invn = (float*)(AB + 40902656);
    float* mmk = invn + 256;
    float* mmp = mmk + 4096;

    norm_kernel<<<dim3(256), dim3(256), 0, stream>>>(b, invn);
    stats_kernel<<<dim3(79), dim3(256), 0, stream>>>(mask, mmk, mmp);
    splitA_kernel<<<dim3(1024), dim3(256), 0, stream>>>(b, invn, Ahi, Alo);
    splitB_kernel<<<dim3(993, 4), dim3(256), 0, stream>>>(f, Bhi, Blo);
    gemm_kernel<<<dim3(8, 32, 4), dim3(256), 0, stream>>>(Ahi, Alo, Bhi, Blo, Rt);
    diag1_kernel<<<dim3(3969, 4), dim3(256), 0, stream>>>(Rt, D1);
    epilogue_kernel<<<dim3(63, 8, 4), dim3(256), 0, stream>>>(D1, mmk, mmp, out);
}

// Round 3
// 375.388 us; speedup vs baseline: 2.0974x; 1.0727x over previous
//
#include <hip/hip_runtime.h>
#include <math.h>

#define NB 4
#define NC 64
#define NL 1024   // 32x32 kernel-patch grid
#define NP 3969   // 63x63 correlation positions
#define PHW 63

typedef unsigned short ushort_t;
typedef __attribute__((ext_vector_type(8))) short short8;
typedef __attribute__((ext_vector_type(16))) float floatx16;

// raw workgroup barrier: waits LDS ops only (lgkmcnt), does NOT drain vmcnt,
// so global prefetch loads stay in flight across the barrier.
__device__ inline void wg_barrier() {
    asm volatile("s_waitcnt lgkmcnt(0)" ::: "memory");
    __builtin_amdgcn_s_barrier();
    asm volatile("" ::: "memory");
}

// ---------------- kernel 1: per-(b,c) inverse L2 norm of b ----------------
__global__ __launch_bounds__(256) void norm_kernel(const float* __restrict__ bsrc,
                                                   float* __restrict__ invn) {
    int bc = blockIdx.x;  // 0..255
    const float* src = bsrc + (size_t)bc * 4096;
    float s = 0.f;
    for (int i = threadIdx.x; i < 4096; i += 256) { float v = src[i]; s += v * v; }
#pragma unroll
    for (int off = 32; off > 0; off >>= 1) s += __shfl_down(s, off, 64);
    __shared__ float part[4];
    if ((threadIdx.x & 63) == 0) part[threadIdx.x >> 6] = s;
    __syncthreads();
    if (threadIdx.x == 0) {
        float t = part[0] + part[1] + part[2] + part[3];
        invn[bc] = 1.0f / sqrtf(t + 1e-8f);
    }
}

// ---------------- kernel 2: patch means of (1-mask) -----------------------
__global__ __launch_bounds__(256) void stats_kernel(const float* __restrict__ mask,
                                                    float* __restrict__ mmk,
                                                    float* __restrict__ mmp) {
    int id = blockIdx.x * 256 + threadIdx.x;
    if (id < NB * NL) {
        int b = id >> 10, l = id & 1023;
        int lh = l >> 5, lw = l & 31;
        const float* m = mask + b * 4096;
        float s = 0.f;
#pragma unroll
        for (int i = 0; i < 4; ++i) {
            int r = min(max(2 * lh - 1 + i, 0), 63);
#pragma unroll
            for (int j = 0; j < 4; ++j) {
                int c = min(max(2 * lw - 1 + j, 0), 63);
                s += 1.0f - m[r * 64 + c];
            }
        }
        mmk[id] = s * (1.0f / 16.0f);
    } else {
        int id2 = id - NB * NL;
        if (id2 < NB * NP) {
            int b = id2 / NP, p = id2 - b * NP;
            int ph = p / PHW, pw = p - ph * PHW;
            const float* m = mask + b * 4096;
            float s = 0.f;
#pragma unroll
            for (int i = 0; i < 4; ++i) {
                int r = min(max(ph - 1 + i, 0), 63);
#pragma unroll
                for (int j = 0; j < 4; ++j) {
                    int c = min(max(pw - 1 + j, 0), 63);
                    s += 1.0f - m[r * 64 + c];
                }
            }
            mmp[id2] = s * (1.0f / 16.0f);
        }
    }
}

// ------------- split helper: fp32 -> bf16 hi + bf16 residual --------------
__device__ inline void split_bf16(float v, ushort_t& hv, ushort_t& lv) {
    unsigned u = __float_as_uint(v);
    unsigned rr = u + 0x7FFFu + ((u >> 16) & 1u);
    hv = (ushort_t)(rr >> 16);
    float fh = __uint_as_float(((unsigned)hv) << 16);
    float remv = v - fh;
    unsigned u2 = __float_as_uint(remv);
    unsigned rr2 = u2 + 0x7FFFu + ((u2 >> 16) & 1u);
    lv = (ushort_t)(rr2 >> 16);
}

// ---------------- kernel 3a: split A via LDS row staging ------------------
// A[b][l][k], k = c*16 + i*4 + j.  Block = one (b, lh): stage 4 b-rows for
// all 64 c coalesced into LDS, then compute 32 lw x 64 c patches.
__global__ __launch_bounds__(256) void splitA_kernel(const float* __restrict__ bsrc,
                                                     const float* __restrict__ invn,
                                                     ushort_t* __restrict__ Ahi,
                                                     ushort_t* __restrict__ Alo) {
    __shared__ float fl[64 * 257];   // [c][i*64+s], pad 1 dword per c
    int lh = blockIdx.x;   // 0..31
    int b  = blockIdx.y;
    int t  = threadIdx.x;
#pragma unroll
    for (int q = 0; q < 64; ++q) {
        int idx = t + (q << 8);
        int c = idx >> 8, rem = idx & 255;
        int i = rem >> 6, s = rem & 63;
        int r = min(max(2 * lh - 1 + i, 0), 63);
        fl[c * 257 + rem] = bsrc[(((size_t)((b << 6) + c)) << 12) + (r << 6) + s];
    }
    __syncthreads();
#pragma unroll
    for (int q = 0; q < 8; ++q) {
        int pair = t + (q << 8);        // 0..2047
        int c = pair & 63, lw = pair >> 6;
        float scale = invn[(b << 6) + c];
        const float* row = fl + c * 257;
        __align__(16) ushort_t h[16];
        __align__(16) ushort_t lo[16];
#pragma unroll
        for (int i = 0; i < 4; ++i)
#pragma unroll
            for (int j = 0; j < 4; ++j) {
                int s = min(max(2 * lw - 1 + j, 0), 63);
                split_bf16(row[i * 64 + s] * scale, h[i * 4 + j], lo[i * 4 + j]);
            }
        size_t base = ((((size_t)b << 10) + (lh << 5) + lw) << 10) + (c << 4);
        *(uint4*)(Ahi + base)     = *(uint4*)h;
        *(uint4*)(Ahi + base + 8) = *(uint4*)(h + 8);
        *(uint4*)(Alo + base)     = *(uint4*)lo;
        *(uint4*)(Alo + base + 8) = *(uint4*)(lo + 8);
    }
}

// ---------------- kernel 3b: split B via LDS row staging ------------------
// B[b][p][k]. Block = one (b, ph): stage 4 f-rows for all 64 c, compute
// 63 pw x 64 c patches.
__global__ __launch_bounds__(256) void splitB_kernel(const float* __restrict__ fsrc,
                                                     ushort_t* __restrict__ Bhi,
                                                     ushort_t* __restrict__ Blo) {
    __shared__ float fl[64 * 257];
    int ph = blockIdx.x;   // 0..62
    int b  = blockIdx.y;
    int t  = threadIdx.x;
#pragma unroll
    for (int q = 0; q < 64; ++q) {
        int idx = t + (q << 8);
        int c = idx >> 8, rem = idx & 255;
        int i = rem >> 6, s = rem & 63;
        int r = min(max(ph - 1 + i, 0), 63);
        fl[c * 257 + rem] = fsrc[(((size_t)((b << 6) + c)) << 12) + (r << 6) + s];
    }
    __syncthreads();
#pragma unroll
    for (int q = 0; q < 16; ++q) {
        int pair = t + (q << 8);        // 0..4095, valid < 4032
        int c = pair & 63, pw = pair >> 6;
        if (pw < PHW) {
            const float* row = fl + c * 257;
            __align__(16) ushort_t h[16];
            __align__(16) ushort_t lo[16];
#pragma unroll
            for (int i = 0; i < 4; ++i)
#pragma unroll
                for (int j = 0; j < 4; ++j) {
                    int s = min(max(pw - 1 + j, 0), 63);
                    split_bf16(row[i * 64 + s], h[i * 4 + j], lo[i * 4 + j]);
                }
            size_t base = (((size_t)b * NP + (size_t)ph * PHW + pw) << 10) + (c << 4);
            *(uint4*)(Bhi + base)     = *(uint4*)h;
            *(uint4*)(Bhi + base + 8) = *(uint4*)(h + 8);
            *(uint4*)(Blo + base)     = *(uint4*)lo;
            *(uint4*)(Blo + base + 8) = *(uint4*)(lo + 8);
        }
    }
}

// ---------------- kernel 4: MFMA GEMM, split-bf16, pipelined --------------
// Rt[b][p][l] = sum_k B[p][k] * A[l][k]
// Block 128l x 128p, 4 waves 2x2, wave tile 64x64 = 2x2 of 32x32x16 MFMA.
// Raw barriers (lgkm-only) keep next-slab global loads in flight across
// the MFMA phase.
__global__ __launch_bounds__(256) void gemm_kernel(
    const ushort_t* __restrict__ Ahi, const ushort_t* __restrict__ Alo,
    const ushort_t* __restrict__ Bhi, const ushort_t* __restrict__ Blo,
    float* __restrict__ Rt) {
    __shared__ ushort_t sAh[4096], sAl[4096], sBh[4096], sBl[4096];

    int l0 = blockIdx.x << 7;
    int p0 = blockIdx.y << 7;
    int b  = blockIdx.z;
    int tid = threadIdx.x;
    int lane = tid & 63, wave = tid >> 6;
    int srow = tid >> 1, shalf = tid & 1;

    const ushort_t* gAh = Ahi + ((size_t)b << 20) + (((size_t)(l0 + srow)) << 10) + (shalf << 4);
    const ushort_t* gAl = Alo + ((size_t)b << 20) + (((size_t)(l0 + srow)) << 10) + (shalf << 4);
    bool pv = (p0 + srow) < NP;
    size_t bgoff = ((size_t)b * NP + (size_t)(p0 + srow)) << 10;
    const ushort_t* gBh = Bhi + bgoff + (shalf << 4);
    const ushort_t* gBl = Blo + bgoff + (shalf << 4);

    floatx16 acc[2][2];
#pragma unroll
    for (int a = 0; a < 2; ++a)
#pragma unroll
        for (int q = 0; q < 2; ++q)
#pragma unroll
            for (int r = 0; r < 16; ++r) acc[a][q][r] = 0.f;

    int pq = (wave & 1) << 6, lq = (wave >> 1) << 6;
    int x = lane & 31, kg = lane >> 5;
    int wbase = ((shalf << 8) + srow) << 3;

    short8 rA[8], rB[8];
    const short8 z = {0, 0, 0, 0, 0, 0, 0, 0};

#define LOAD8(r, kb)                                                  \
    do {                                                              \
        int koff = (kb) << 5;                                         \
        r[0] = *(const short8*)(gAh + koff);                          \
        r[1] = *(const short8*)(gAh + koff + 8);                      \
        r[2] = *(const short8*)(gAl + koff);                          \
        r[3] = *(const short8*)(gAl + koff + 8);                      \
        r[4] = pv ? *(const short8*)(gBh + koff) : z;                 \
        r[5] = pv ? *(const short8*)(gBh + koff + 8) : z;             \
        r[6] = pv ? *(const short8*)(gBl + koff) : z;                 \
        r[7] = pv ? *(const short8*)(gBl + koff + 8) : z;             \
    } while (0)

#define STORE8(r)                                                     \
    do {                                                              \
        *(short8*)(sAh + wbase)        = r[0];                        \
        *(short8*)(sAh + wbase + 1024) = r[1];                        \
        *(short8*)(sAl + wbase)        = r[2];                        \
        *(short8*)(sAl + wbase + 1024) = r[3];                        \
        *(short8*)(sBh + wbase)        = r[4];                        \
        *(short8*)(sBh + wbase + 1024) = r[5];                        \
        *(short8*)(sBl + wbase)        = r[6];                        \
        *(short8*)(sBl + wbase + 1024) = r[7];                        \
    } while (0)

#define COMPUTE()                                                                                      \
    do {                                                                                               \
        _Pragma("unroll")                                                                              \
        for (int h = 0; h < 2; ++h) {                                                                  \
            int cc = (h << 1) + kg;                                                                    \
            int cbase = cc << 10;                                                                      \
            short8 fAh[2], fAl[2], fBh[2], fBl[2];                                                     \
            _Pragma("unroll")                                                                          \
            for (int t2 = 0; t2 < 2; ++t2) {                                                           \
                int ai = cbase + ((lq + (t2 << 5) + x) << 3);                                          \
                int bi = cbase + ((pq + (t2 << 5) + x) << 3);                                          \
                fAh[t2] = *(const short8*)(sAh + ai);                                                  \
                fAl[t2] = *(const short8*)(sAl + ai);                                                  \
                fBh[t2] = *(const short8*)(sBh + bi);                                                  \
                fBl[t2] = *(const short8*)(sBl + bi);                                                  \
            }                                                                                          \
            _Pragma("unroll")                                                                          \
            for (int pt = 0; pt < 2; ++pt)                                                             \
                _Pragma("unroll")                                                                      \
                for (int lt = 0; lt < 2; ++lt) {                                                       \
                    acc[pt][lt] = __builtin_amdgcn_mfma_f32_32x32x16_bf16(fBh[pt], fAh[lt], acc[pt][lt], 0, 0, 0); \
                    acc[pt][lt] = __builtin_amdgcn_mfma_f32_32x32x16_bf16(fBh[pt], fAl[lt], acc[pt][lt], 0, 0, 0); \
                    acc[pt][lt] = __builtin_amdgcn_mfma_f32_32x32x16_bf16(fBl[pt], fAh[lt], acc[pt][lt], 0, 0, 0); \
                }                                                                                      \
        }                                                                                              \
    } while (0)

    LOAD8(rA, 0);
    for (int kb = 0; kb < 32; kb += 2) {
        wg_barrier();              // all waves done reading previous LDS tile
        STORE8(rA);                // compiler inserts vmcnt waits for rA only
        LOAD8(rB, kb + 1);         // prefetch next slab (in flight during MFMA)
        wg_barrier();              // lgkm drain: LDS writes visible
        COMPUTE();
        wg_barrier();
        STORE8(rB);
        if (kb + 2 < 32) LOAD8(rA, kb + 2);
        wg_barrier();
        COMPUTE();
    }

    // store: D row = p (first operand), col = l (second operand)
#pragma unroll
    for (int pt = 0; pt < 2; ++pt)
#pragma unroll
        for (int lt = 0; lt < 2; ++lt)
#pragma unroll
            for (int r = 0; r < 16; ++r) {
                int p = p0 + pq + (pt << 5) + (r & 3) + ((r >> 2) << 3) + (kg << 2);
                int l = l0 + lq + (lt << 5) + x;
                if (p < NP) Rt[((size_t)b * NP + p) * NL + l] = acc[pt][lt][r];
            }
#undef LOAD8
#undef STORE8
#undef COMPUTE
}

// ---------------- kernel 5: first diag3 pass ------------------------------
__global__ __launch_bounds__(256) void diag1_kernel(const float* __restrict__ Rt,
                                                    float* __restrict__ D1) {
    int p = blockIdx.x, b = blockIdx.y;
    int t = threadIdx.x;
    const float* base = Rt + ((size_t)b * NP + p) * NL;
    int l4 = t << 2;
    float4 r = *(const float4*)(base + l4);
    if (p > 0) {
        const float* pm = base - NL;
        r.x += (l4 > 0) ? pm[l4 - 1] : 0.f;
        r.y += pm[l4];
        r.z += pm[l4 + 1];
        r.w += pm[l4 + 2];
    }
    if (p < NP - 1) {
        const float* pp = base + NL;
        r.x += pp[l4 + 1];
        r.y += pp[l4 + 2];
        r.z += pp[l4 + 3];
        r.w += (l4 + 4 < NL) ? pp[l4 + 4] : 0.f;
    }
    *(float4*)(D1 + ((size_t)b * NP + p) * NL + l4) = r;
}

// ---------------- kernel 6: second diag3 (transposed) + mask + softmax ----
#define FS_STRIDE 1028
__global__ __launch_bounds__(256) void epilogue_kernel(const float* __restrict__ D1,
                                                       const float* __restrict__ mmkA,
                                                       const float* __restrict__ mmpA,
                                                       float* __restrict__ out) {
    __shared__ float Fs[8 * FS_STRIDE];
    __shared__ float gsum[8];
    int ph  = blockIdx.x;        // 0..62
    int pw0 = blockIdx.y * 8;
    int b   = blockIdx.z;
    int tid = threadIdx.x;

    {
        int pwl = tid & 7, lpart = tid >> 3;
        int pw = pw0 + pwl;
        bool pvalid = pw < PHW;
        int p = ph * PHW + pw;
        const float* Db = D1 + (size_t)b * NP * NL;
        float mmpv = 0.f;
        int p2arr[3]; int pokm = 0;
        if (pvalid) {
            mmpv = mmpA[b * NP + p];
            int tp = pw * PHW + ph;
#pragma unroll
            for (int dd = 0; dd < 3; ++dd) {
                int pq2 = tp + dd - 1;
                if (pq2 >= 0 && pq2 < NP) {
                    int qh = pq2 / PHW, qw = pq2 - qh * PHW;
                    p2arr[dd] = qw * PHW + qh;
                    pokm |= (1 << dd);
                } else p2arr[dd] = 0;
            }
        } else { p2arr[0] = p2arr[1] = p2arr[2] = 0; }

        for (int k = 0; k < 32; ++k) {
            int l = lpart + (k << 5);
            int tl = ((l & 31) << 5) | (l >> 5);
            float Fv = 0.f;
#pragma unroll
            for (int dd = 0; dd < 3; ++dd) {
                int lqi = tl + dd - 1;
                if (((pokm >> dd) & 1) && lqi >= 0 && lqi < NL) {
                    int l2 = ((lqi & 31) << 5) | (lqi >> 5);
                    Fv += Db[(size_t)p2arr[dd] * NL + l2];
                }
            }
            float mmkv = mmkA[b * NL + l];
            float mmv = (((mmkv > mmpv) && (mmpv > 0.5f)) || (mmkv == 1.0f)) ? 1.0f : 0.0f;
            float logit = pvalid ? (Fv * mmv * 10.0f) : 0.0f;
            Fs[pwl * FS_STRIDE + l] = logit;
        }
    }
    __syncthreads();

    {
        int pw2 = tid >> 5;
        int tl  = tid & 31;
        float m = -3.0e38f;
        for (int k = 0; k < 32; ++k)
            m = fmaxf(m, Fs[pw2 * FS_STRIDE + tl + (k << 5)]);
#pragma unroll
        for (int off = 16; off >= 1; off >>= 1) m = fmaxf(m, __shfl_xor(m, off, 64));
        float s = 0.f;
        for (int k = 0; k < 32; ++k) {
            int idx = pw2 * FS_STRIDE + tl + (k << 5);
            float e = expf(Fs[idx] - m);
            Fs[idx] = e;
            s += e;
        }
#pragma unroll
        for (int off = 16; off >= 1; off >>= 1) s += __shfl_xor(s, off, 64);
        if (tl == 0) gsum[pw2] = s;
    }
    __syncthreads();

    {
        int pwl = tid & 7, lp3 = tid >> 3;
        int pw = pw0 + pwl;
        bool pvalid = pw < PHW;
        float rinv = 1.0f / gsum[pwl];
        if (pvalid) {
            int p = ph * PHW + pw;
            for (int k = 0; k < 32; ++k) {
                int l = lp3 + (k << 5);
                float v = Fs[pwl * FS_STRIDE + l] * rinv;
                out[((size_t)(b * NL + l)) * NP + p] = v;
            }
        }
    }
}

extern "C" void kernel_launch(void* const* d_in, const int* in_sizes, int n_in,
                              void* d_out, int out_size, void* d_ws, size_t ws_size,
                              hipStream_t stream) {
    const float* f    = (const float*)d_in[0];
    const float* b    = (const float*)d_in[1];
    const float* mask = (const float*)d_in[2];
    float* out = (float*)d_out;

    float* Rt = (float*)d_ws;
    ushort_t* AB = (ushort_t*)(Rt + 16257024);
    ushort_t* Ahi = AB;
    ushort_t* Alo = Ahi + 4194304;
    ushort_t* Bhi = Alo + 4194304;
    ushort_t* Blo = Bhi + 16257024;
    float* D1 = (float*)AB;                    // overlay, used after GEMM
    float* invn = (float*)(AB + 40902656);
    float* mmk = invn + 256;
    float* mmp = mmk + 4096;

    norm_kernel<<<dim3(256), dim3(256), 0, stream>>>(b, invn);
    stats_kernel<<<dim3(79), dim3(256), 0, stream>>>(mask, mmk, mmp);
    splitA_kernel<<<dim3(32, 4), dim3(256), 0, stream>>>(b, invn, Ahi, Alo);
    splitB_kernel<<<dim3(63, 4), dim3(256), 0, stream>>>(f, Bhi, Blo);
    gemm_kernel<<<dim3(8, 32, 4), dim3(256), 0, stream>>>(Ahi, Alo, Bhi, Blo, Rt);
    diag1_kernel<<<dim3(3969, 4), dim3(256), 0, stream>>>(Rt, D1);
    epilogue_kernel<<<dim3(63, 8, 4), dim3(256), 0, stream>>>(D1, mmk, mmp, out);
}